// Round 15
// baseline (1928.835 us; speedup 1.0000x reference)
//
#include <hip/hip_runtime.h>
#include <hip/hip_bf16.h>
#include <hip/hip_fp16.h>
#include <math.h>

#define B_ 16384
#define D_ 2048
#define H_ 2048
#define E_ 6
#define C_ 1024

#define HALF_ (128 * 64)   // elements per half-tile (128 rows x 64 k, bf16)

typedef __attribute__((ext_vector_type(8))) short short8;
typedef __attribute__((ext_vector_type(4))) float f32x4;

__device__ __forceinline__ unsigned short f2bf(float f) {
    __hip_bfloat16 h = __float2bfloat16(f);
    return *reinterpret_cast<unsigned short*>(&h);
}

__device__ __forceinline__ unsigned short f2h(float f) {
    __half h = __float2half(f);
    return *reinterpret_cast<unsigned short*>(&h);
}

__device__ __forceinline__ float h2f(unsigned short u) {
    __half h = *reinterpret_cast<__half*>(&u);
    return __half2float(h);
}

__device__ __forceinline__ void async_copy16(const unsigned short* g, unsigned short* l) {
    __builtin_amdgcn_global_load_lds(
        (const __attribute__((address_space(1))) unsigned int*)(g),
        (__attribute__((address_space(3))) unsigned int*)(l), 16, 0, 0);
}

// ---------------- gate: fp64 logits, top-3, softmax, routing lists + fused x->bf16 cast ----------------
__global__ void gate_kernel(const float* __restrict__ x, const float* __restrict__ gW,
                            const float* __restrict__ gb, float* __restrict__ gw_out,
                            int* __restrict__ counts, int* __restrict__ rowlist,
                            float* __restrict__ wtslist, unsigned short* __restrict__ xb) {
    int wave = threadIdx.x >> 6;
    int lane = threadIdx.x & 63;
    int row  = blockIdx.x * 4 + wave;
    const float* xr = x + (size_t)row * D_;
    unsigned short* xbr = xb + (size_t)row * D_;
    double acc[E_] = {0, 0, 0, 0, 0, 0};
    for (int i = 0; i < D_ / 64; ++i) {
        int d = i * 64 + lane;
        float xf = xr[d];
        xbr[d] = f2bf(xf);
        double xv = (double)xf;
#pragma unroll
        for (int e = 0; e < E_; ++e) acc[e] += xv * (double)gW[e * D_ + d];
    }
#pragma unroll
    for (int off = 32; off > 0; off >>= 1) {
#pragma unroll
        for (int e = 0; e < E_; ++e) acc[e] += __shfl_down(acc[e], off);
    }
    if (lane == 0) {
        double lg[E_];
#pragma unroll
        for (int e = 0; e < E_; ++e) lg[e] = acc[e] + (double)gb[e];
        bool used[E_] = {false, false, false, false, false, false};
        int idx[3]; double val[3];
        for (int k = 0; k < 3; ++k) {
            int best = -1; double bv = -1e300;
            for (int e = 0; e < E_; ++e)
                if (!used[e] && lg[e] > bv) { bv = lg[e]; best = e; }
            used[best] = true; idx[k] = best; val[k] = bv;
        }
        double m = val[0];
        double w[3]; double s = 0.0;
        for (int k = 0; k < 3; ++k) { w[k] = exp(val[k] - m); s += w[k]; }
        float gwv[E_] = {0.f, 0.f, 0.f, 0.f, 0.f, 0.f};
        for (int k = 0; k < 3; ++k) gwv[idx[k]] = (float)(w[k] / s);
#pragma unroll
        for (int e = 0; e < E_; ++e) gw_out[(size_t)row * E_ + e] = gwv[e];
        for (int k = 0; k < 3; ++k) {
            int e = idx[k];
            int pos = atomicAdd(&counts[e], 1);
            rowlist[(size_t)e * B_ + pos] = row * 3 + k;   // global slot id
            wtslist[(size_t)e * B_ + pos] = (float)(w[k] / s);
        }
    }
}

// ---------------- f32 -> bf16 cast (vectorized) ----------------
__global__ void cast_f32_bf16(const float* __restrict__ in, unsigned short* __restrict__ out, int n4) {
    int i = blockIdx.x * blockDim.x + threadIdx.x;
    if (i < n4) {
        float4 v = ((const float4*)in)[i];
        ushort4 u;
        u.x = f2bf(v.x); u.y = f2bf(v.y); u.z = f2bf(v.z); u.w = f2bf(v.w);
        ((ushort4*)out)[i] = u;
    }
}

// =====================================================================
// 256x256 tile, BK=64, 8 waves (2M x 4N; per-wave 128x64), 2 K-tile LDS
// buffers (128 KiB).  m-MAJOR SOFTWARE-PIPELINED tile body: read B-frags
// once at tile top; then for each of 8 m-fragments, ISSUE the next m's
// two A ds_reads and run 8 MFMAs on the current m.  No manual lgkm
// drains -- the compiler emits counted lgkmcnt(N) (m97 evidence), so
// each 2-read retire hides under the previous ~155-cyc MFMA burst.
// Three hazard barriers per tile: after m3 (B consumed CU-wide ->
// STAGE_B), after m7 (A consumed -> STAGE_A), boundary vmcnt(8)+barrier
// (tile t+1 resident, tile t+2's 8 stage-loads in flight; drains only
// in epilogue).
//
// LDS: per half [128][64] bf16, granule(16B)-XOR swizzle p^=(row&7)
// (0-conflict, verified rounds 0-10); staging pre-applies the inverse
// permutation on the GLOBAL source address (linear LDS dest).
// =====================================================================

#define STAGE_A(dstbuf, koff)                                                    \
    _Pragma("unroll")                                                            \
    for (int h_ = 0; h_ < 2; ++h_)                                               \
        _Pragma("unroll")                                                        \
        for (int j_ = 0; j_ < 2; ++j_)                                           \
            async_copy16(asrc[h_][j_] + (koff),                                  \
                         (dstbuf) + h_ * HALF_ + (j_ * 512 + tid) * 8);

#define STAGE_B(dstbuf, koff)                                                    \
    _Pragma("unroll")                                                            \
    for (int h_ = 0; h_ < 2; ++h_)                                               \
        _Pragma("unroll")                                                        \
        for (int j_ = 0; j_ < 2; ++j_)                                           \
            async_copy16(bsrc[h_][j_] + (koff),                                  \
                         (dstbuf) + h_ * HALF_ + (j_ * 512 + tid) * 8);

#define MFMA_BF16 __builtin_amdgcn_mfma_f32_16x16x32_bf16

#define BARRIER_FENCE()                                                          \
    __builtin_amdgcn_s_barrier();                                                \
    __builtin_amdgcn_sched_barrier(0);

#define GEMM_CORE(KDIM)                                                          \
    int lane = tid & 63;                                                         \
    int wv = tid >> 6;                                                           \
    int wr = wv >> 2;   /* 0..1: M half   */                                     \
    int wc = wv & 3;    /* 0..3: N strip  */                                     \
    int fm = lane & 15;                                                          \
    int kg = lane >> 4;                                                          \
    unsigned g0 = (unsigned)((kg ^ (fm & 7)) * 8);                               \
    unsigned g1 = (unsigned)(((4 + kg) ^ (fm & 7)) * 8);                         \
    unsigned aRB = (unsigned)(wr * HALF_ + fm * 64);                             \
    unsigned bRB = (unsigned)((wc >> 1) * HALF_ + ((wc & 1) * 64 + fm) * 64);    \
    f32x4 acc[8][4] = {};                                                        \
    const int NT = (KDIM) / 64;                                                  \
    STAGE_A(As, 0) STAGE_B(Bs, 0)                                                \
    STAGE_A(As + 2 * HALF_, 64) STAGE_B(Bs + 2 * HALF_, 64)                      \
    asm volatile("s_waitcnt vmcnt(8)" ::: "memory");                             \
    BARRIER_FENCE()                                                              \
    for (int t = 0; t < NT; ++t) {                                               \
        unsigned short* Ab = As + (t & 1) * (2 * HALF_);                         \
        unsigned short* Bb = Bs + (t & 1) * (2 * HALF_);                         \
        const bool st = (t + 2 < NT);                                            \
        const int koff = (t + 2) * 64;                                           \
        const unsigned short* Ar0 = Ab + aRB + g0;                               \
        const unsigned short* Ar1 = Ab + aRB + g1;                               \
        const unsigned short* Br0 = Bb + bRB + g0;                               \
        const unsigned short* Br1 = Bb + bRB + g1;                               \
        short8 bQ[2][2], bR[2][2];                                               \
        _Pragma("unroll")                                                        \
        for (int n = 0; n < 2; ++n) {                                            \
            bQ[n][0] = *(const short8*)(Br0 + n * 1024);                         \
            bQ[n][1] = *(const short8*)(Br1 + n * 1024);                         \
            bR[n][0] = *(const short8*)(Br0 + (2 + n) * 1024);                   \
            bR[n][1] = *(const short8*)(Br1 + (2 + n) * 1024);                   \
        }                                                                        \
        short8 aC0 = *(const short8*)(Ar0);                                      \
        short8 aC1 = *(const short8*)(Ar1);                                      \
        __builtin_amdgcn_s_setprio(1);                                           \
        _Pragma("unroll")                                                        \
        for (int m = 0; m < 8; ++m) {                                            \
            short8 aN0, aN1;                                                     \
            if (m < 7) {                                                         \
                aN0 = *(const short8*)(Ar0 + (m + 1) * 1024);                    \
                aN1 = *(const short8*)(Ar1 + (m + 1) * 1024);                    \
            }                                                                    \
            acc[m][0] = MFMA_BF16(aC0, bQ[0][0], acc[m][0], 0, 0, 0);            \
            acc[m][0] = MFMA_BF16(aC1, bQ[0][1], acc[m][0], 0, 0, 0);            \
            acc[m][1] = MFMA_BF16(aC0, bQ[1][0], acc[m][1], 0, 0, 0);            \
            acc[m][1] = MFMA_BF16(aC1, bQ[1][1], acc[m][1], 0, 0, 0);            \
            acc[m][2] = MFMA_BF16(aC0, bR[0][0], acc[m][2], 0, 0, 0);            \
            acc[m][2] = MFMA_BF16(aC1, bR[0][1], acc[m][2], 0, 0, 0);            \
            acc[m][3] = MFMA_BF16(aC0, bR[1][0], acc[m][3], 0, 0, 0);            \
            acc[m][3] = MFMA_BF16(aC1, bR[1][1], acc[m][3], 0, 0, 0);            \
            if (m < 7) { aC0 = aN0; aC1 = aN1; }                                 \
            if (m == 3) {                                                        \
                __builtin_amdgcn_s_setprio(0);                                   \
                BARRIER_FENCE()   /* B(c) consumed CU-wide (used by m0-3) */     \
                if (st) { STAGE_B(Bb, koff) }                                    \
                __builtin_amdgcn_s_setprio(1);                                   \
            }                                                                    \
        }                                                                        \
        __builtin_amdgcn_s_setprio(0);                                           \
        BARRIER_FENCE()           /* A(c) consumed CU-wide */                    \
        if (st) { STAGE_A(Ab, koff) }                                            \
        if (st) asm volatile("s_waitcnt vmcnt(8)" ::: "memory");                 \
        else    asm volatile("s_waitcnt vmcnt(0)" ::: "memory");                 \
        __builtin_amdgcn_sched_barrier(0);                                       \
        BARRIER_FENCE()           /* tile t+1 visible to all waves */            \
    }

// ---------------- GEMM1: hbuf[compact] = gelu(x[row] @ W1[e]^T + b1[e]) ----------------
__global__ __launch_bounds__(512, 2) void gemm1_kernel(
    const unsigned short* __restrict__ xb, const unsigned short* __restrict__ W1b,
    const float* __restrict__ b1, const int* __restrict__ counts,
    const int* __restrict__ rowlist, unsigned short* __restrict__ hbuf) {
    int e = blockIdx.z;
    int cnt = counts[e];
    int eoff = 0;
#pragma unroll
    for (int i = 0; i < E_; ++i) if (i < e) eoff += counts[i];   // compact prefix
    // XCD-panel rasterization: the 8 n-blocks of an m-panel land on one XCD
    int flat = blockIdx.x;                      // grid.x = 8 * 64 = 512
    int p  = (flat & 7) + ((flat >> 6) << 3);   // m-panel 0..63
    int nb = (flat >> 3) & 7;                   // n-block 0..7
    int m0 = p * 256;
    if (m0 >= cnt) return;
    int n0 = nb * 256;

    __shared__ __align__(16) unsigned short As[4 * HALF_];   // 64 KiB
    __shared__ __align__(16) unsigned short Bs[4 * HALF_];   // 64 KiB
    int tid = threadIdx.x;
    const int* rlist = rowlist + (size_t)e * B_;

    // staging source pointers: thread owns granule (rb, gth) of each half
    int rb = tid >> 3;
    int gth = ((tid & 7) ^ (rb & 7)) * 8;
    const unsigned short* asrc[2][2];
    const unsigned short* bsrc[2][2];
#pragma unroll
    for (int h = 0; h < 2; ++h)
#pragma unroll
        for (int j = 0; j < 2; ++j) {
            int r = h * 128 + j * 64 + rb;
            int idx = m0 + r; if (idx >= cnt) idx = cnt - 1;
            asrc[h][j] = xb + (size_t)(rlist[idx] / 3) * D_ + gth;
            bsrc[h][j] = W1b + (size_t)e * H_ * D_ + (size_t)(n0 + r) * D_ + gth;
        }

    GEMM_CORE(D_)

    int rlim = cnt - m0;
#pragma unroll
    for (int m = 0; m < 8; ++m) {
#pragma unroll
        for (int i = 0; i < 4; ++i) {
            int r = wr * 128 + m * 16 + kg * 4 + i;
            if (r < rlim) {
                size_t base = (size_t)(eoff + m0 + r) * H_ + n0;   // compact row
#pragma unroll
                for (int n = 0; n < 4; ++n) {
                    int col = wc * 64 + n * 16 + fm;
                    float v = acc[m][n][i] + b1[e * H_ + n0 + col];
                    v = 0.5f * v * (1.0f + erff(v * 0.70710678118654752f)); // exact GELU
                    hbuf[base + col] = f2bf(v);
                }
            }
        }
    }
}

// ---------------- GEMM2: sbuf16[slot] = f16(w * (hbuf[compact] @ W2[e]^T + b2[e])) ----------------
__global__ __launch_bounds__(512, 2) void gemm2_kernel(
    const unsigned short* __restrict__ hbuf, const unsigned short* __restrict__ W2b,
    const float* __restrict__ b2, const int* __restrict__ counts,
    const int* __restrict__ rowlist, const float* __restrict__ wtslist,
    unsigned short* __restrict__ sbuf, float* __restrict__ out) {
    int e = blockIdx.z;
    int cnt = counts[e];
    int eoff = 0;
#pragma unroll
    for (int i = 0; i < E_; ++i) if (i < e) eoff += counts[i];
    int flat = blockIdx.x;                      // grid.x = 4 * 64 = 256
    int p  = (flat & 7) + ((flat >> 5) << 3);   // m-panel 0..63
    int nb = (flat >> 3) & 3;    // n-block 0..3
    int m0 = p * 256;
    if (m0 >= cnt) return;
    int n0 = nb * 256;

    __shared__ __align__(16) unsigned short As[4 * HALF_];
    __shared__ __align__(16) unsigned short Bs[4 * HALF_];
    int tid = threadIdx.x;
    const int* rlist = rowlist + (size_t)e * B_;
    const float* wlist = wtslist + (size_t)e * B_;

    int rb = tid >> 3;
    int gth = ((tid & 7) ^ (rb & 7)) * 8;
    const unsigned short* asrc[2][2];
    const unsigned short* bsrc[2][2];
#pragma unroll
    for (int h = 0; h < 2; ++h)
#pragma unroll
        for (int j = 0; j < 2; ++j) {
            int r = h * 128 + j * 64 + rb;
            int idx = m0 + r; if (idx >= cnt) idx = cnt - 1;
            asrc[h][j] = hbuf + (size_t)(eoff + idx) * H_ + gth;   // contiguous compact rows
            bsrc[h][j] = W2b + (size_t)e * C_ * H_ + (size_t)(n0 + r) * H_ + gth;
        }

    GEMM_CORE(H_)

    int rlim = cnt - m0;
#pragma unroll
    for (int m = 0; m < 8; ++m) {
#pragma unroll
        for (int i = 0; i < 4; ++i) {
            int r = wr * 128 + m * 16 + kg * 4 + i;
            if (r < rlim) {
                int slot = rlist[m0 + r];
                float w  = wlist[m0 + r];
                if (sbuf) {
                    unsigned short* srow = sbuf + (size_t)slot * C_ + n0;  // exclusive ownership
#pragma unroll
                    for (int n = 0; n < 4; ++n) {
                        int col = wc * 64 + n * 16 + fm;
                        srow[col] = f2h((acc[m][n][i] + b2[e * C_ + n0 + col]) * w);
                    }
                } else {
                    float* orow = out + (size_t)(slot / 3) * C_ + n0;
#pragma unroll
                    for (int n = 0; n < 4; ++n) {
                        int col = wc * 64 + n * 16 + fm;
                        atomicAdd(&orow[col], (acc[m][n][i] + b2[e * C_ + n0 + col]) * w);
                    }
                }
            }
        }
    }
}

// ---------------- combine: out[row] = sum of the row's 3 f16 slot rows (f32 accum) ----------------
__global__ void combine_kernel(const unsigned short* __restrict__ sbuf, float* __restrict__ out) {
    int i   = blockIdx.x * 256 + threadIdx.x;   // over B*C/8
    int row = i >> 7;                           // C/8 = 128 short8 per row
    int c8  = i & 127;
    const short8* s8 = (const short8*)sbuf;
    size_t b = (size_t)row * 3 * 128 + c8;
    short8 a = s8[b], d = s8[b + 128], g = s8[b + 256];
    f32x4 lo, hi;
#pragma unroll
    for (int j = 0; j < 4; ++j) {
        lo[j] = h2f((unsigned short)a[j]) + h2f((unsigned short)d[j]) + h2f((unsigned short)g[j]);
        hi[j] = h2f((unsigned short)a[4 + j]) + h2f((unsigned short)d[4 + j]) + h2f((unsigned short)g[4 + j]);
    }
    f32x4* o4 = (f32x4*)(out + (size_t)i * 8);
    __builtin_nontemporal_store(lo, &o4[0]);
    __builtin_nontemporal_store(hi, &o4[1]);
}

extern "C" void kernel_launch(void* const* d_in, const int* in_sizes, int n_in,
                              void* d_out, int out_size, void* d_ws, size_t ws_size,
                              hipStream_t stream) {
    const float* x  = (const float*)d_in[0];
    const float* gW = (const float*)d_in[1];
    const float* gb = (const float*)d_in[2];
    const float* W1 = (const float*)d_in[3];
    const float* b1 = (const float*)d_in[4];
    const float* W2 = (const float*)d_in[5];
    const float* b2 = (const float*)d_in[6];
    float* out    = (float*)d_out;                 // [B, C]
    float* gw_out = out + (size_t)B_ * C_;         // [B, E]

    char* ws = (char*)d_ws;
    size_t off = 0;
    auto alloc = [&](size_t bytes) -> char* {
        char* p = ws + off;
        off = (off + bytes + 255) & ~(size_t)255;
        return p;
    };
    int*            counts  = (int*)alloc(E_ * 4);
    int*            rowlist = (int*)alloc((size_t)E_ * B_ * 4);
    float*          wtslist = (float*)alloc((size_t)E_ * B_ * 4);
    unsigned short* W2b     = (unsigned short*)alloc((size_t)E_ * C_ * H_ * 2);
    unsigned short* hbuf    = (unsigned short*)alloc((size_t)3 * B_ * H_ * 2);
    // union region: {xb (67MB) + W1b (50MB)} live until gemm1; sbuf16 (101MB)
    // live only during gemm2+combine -- fits inside the proven xb+W1b footprint.
    size_t region_off = off;
    unsigned short* xb      = (unsigned short*)alloc((size_t)B_ * D_ * 2);
    unsigned short* W1b     = (unsigned short*)alloc((size_t)E_ * H_ * D_ * 2);
    unsigned short* sbuf    = (unsigned short*)(ws + region_off);
    size_t sbuf_end = region_off + (size_t)3 * B_ * C_ * 2;
    bool use_sbuf = (ws_size == 0) || (sbuf_end <= ws_size);
    (void)in_sizes; (void)n_in; (void)out_size;

    hipMemsetAsync(counts, 0, E_ * 4, stream);
    if (!use_sbuf) hipMemsetAsync(out, 0, (size_t)B_ * C_ * 4, stream);

    gate_kernel<<<B_ / 4, 256, 0, stream>>>(x, gW, gb, gw_out, counts, rowlist, wtslist, xb);
    cast_f32_bf16<<<(E_ * H_ * D_ / 4) / 256, 256, 0, stream>>>(W1, W1b, E_ * H_ * D_ / 4);
    cast_f32_bf16<<<(E_ * C_ * H_ / 4) / 256, 256, 0, stream>>>(W2, W2b, E_ * C_ * H_ / 4);
    gemm1_kernel<<<dim3(8 * (B_ / 256), 1, E_), 512, 0, stream>>>(xb, W1b, b1, counts, rowlist, hbuf);
    gemm2_kernel<<<dim3(4 * (B_ / 256), 1, E_), 512, 0, stream>>>(hbuf, W2b, b2, counts, rowlist, wtslist,
                                                                  use_sbuf ? sbuf : (unsigned short*)nullptr, out);
    if (use_sbuf)
        combine_kernel<<<(B_ * C_ / 8) / 256, 256, 0, stream>>>(sbuf, out);
}